// Round 5
// baseline (720.341 us; speedup 1.0000x reference)
//
#include <hip/hip_runtime.h>
#include <hip/hip_bf16.h>
#include <cstddef>

// B=8, L=1024, E=1024, H=8, d=128
// out = BandedGaussianAttn(values @ Win^T) @ Wout^T
// Identity: Att[q, e(h)] = smooth(values)[q + ofs_h] . Win[e,:]
//   (equal stds -> head-independent smoothing; per-head offset becomes a
//    row shift of the GEMM1 A-operand selected by output column block)
// Pipeline: smooth_cvt (sliding-window 13-tap fp32->bf16 + weight cvt)
//        -> GEMM1 shifted-A (bf16->bf16) -> GEMM2 (bf16->fp32)

#define BATCH 8
#define SEQL  1024
#define EMB   1024
#define VROWS 1040   // 65 strips x 16; VG row r holds smoothed row p = r-4
#define RAD   6
#define RSTRIP 16

typedef unsigned short u16;
typedef __attribute__((ext_vector_type(8))) short s16x8;
typedef __attribute__((ext_vector_type(4))) float f32x4;
typedef __attribute__((ext_vector_type(8))) unsigned short u16x8;
typedef __attribute__((ext_vector_type(4))) unsigned short u16x4;

#define GLOAD_LDS16(g, l)                                                     \
    __builtin_amdgcn_global_load_lds(                                         \
        (const __attribute__((address_space(1))) void*)(g),                   \
        (__attribute__((address_space(3))) void*)(l), 16, 0, 0)

__device__ __forceinline__ u16 f2bf(float f) {
    unsigned u = __builtin_bit_cast(unsigned, f);
    u += 0x7FFF + ((u >> 16) & 1);
    return (u16)(u >> 16);
}

__constant__ float c_w[2 * RAD + 1] = {
    6.075882849823286e-09f, 1.4867195147342979e-06f, 1.3383022576488537e-04f,
    4.431848411938008e-03f, 5.399096651318806e-02f,  2.4197072451914337e-01f,
    3.989422804014327e-01f,
    2.4197072451914337e-01f, 5.399096651318806e-02f, 4.431848411938008e-03f,
    1.3383022576488537e-04f, 1.4867195147342979e-06f, 6.075882849823286e-09f
};
__constant__ int c_ofs[8] = { -3, -2, -1, 0, 0, 1, 2, 3 };

// ---------- smooth_cvt: sliding-window strip version ----------
// blocks [0,520): strip smoothing. b = blk&7 (XCD-local batch), s = blk>>3.
// Each thread: e-chunk of 4 floats, 16 output rows; reads 28 input rows once.
// blocks [520,1544): fp32->bf16 cvt of Win/Wout.
__global__ __launch_bounds__(256) void smooth_cvt(
    const float* __restrict__ values, const unsigned char* __restrict__ mask,
    const float* __restrict__ wi, const float* __restrict__ wo,
    u16* __restrict__ VG, u16* __restrict__ wib, u16* __restrict__ wob)
{
    const int blk = blockIdx.x;
    if (blk < 520) {
        const int b  = blk & 7;            // XCD-local batches
        const int s  = blk >> 3;           // 0..64
        const int r0 = s * RSTRIP;         // output VG rows r0..r0+15
        const int p0 = r0 - 4;             // source row of output r is p = r-4
        const int e  = threadIdx.x * 4;
        const float* vbase = values + (size_t)b * SEQL * EMB + e;
        const unsigned char* mrow = mask + b * SEQL;

        float ax[RSTRIP], ay[RSTRIP], az[RSTRIP], aw[RSTRIP];
        #pragma unroll
        for (int r = 0; r < RSTRIP; ++r) { ax[r]=0.f; ay[r]=0.f; az[r]=0.f; aw[r]=0.f; }

        #pragma unroll
        for (int vi = 0; vi < RSTRIP + 2 * RAD; ++vi) {       // 28 input rows
            const int v = p0 - RAD + vi;
            if (v < 0 || v >= SEQL) continue;                 // uniform branch
            if (mrow[v]) continue;                            // masked_fill row
            const float4 x = *(const float4*)(vbase + (size_t)v * EMB);
            #pragma unroll
            for (int j = -RAD; j <= RAD; ++j) {
                const int rr = vi - RAD - j;                  // compile-time
                if (rr < 0 || rr >= RSTRIP) continue;
                const float w = c_w[j + RAD];
                ax[rr] = fmaf(w, x.x, ax[rr]);
                ay[rr] = fmaf(w, x.y, ay[rr]);
                az[rr] = fmaf(w, x.z, az[rr]);
                aw[rr] = fmaf(w, x.w, aw[rr]);
            }
        }
        u16* obase = VG + (size_t)(b * VROWS + r0) * EMB + e;
        #pragma unroll
        for (int r = 0; r < RSTRIP; ++r) {
            u16x4 o;
            o[0] = f2bf(ax[r]); o[1] = f2bf(ay[r]);
            o[2] = f2bf(az[r]); o[3] = f2bf(aw[r]);
            *(u16x4*)(obase + (size_t)r * EMB) = o;
        }
    } else {
        const int k = (blk - 520) * 256 + threadIdx.x;        // 0..262143
        const float* src = (k < 131072) ? wi : wo;
        u16* dst = (k < 131072) ? wib : wob;
        const size_t off = (size_t)(k & 131071) * 8;
        const float4 a = *(const float4*)(src + off);
        const float4 b4 = *(const float4*)(src + off + 4);
        u16x8 o;
        o[0] = f2bf(a.x);  o[1] = f2bf(a.y);  o[2] = f2bf(a.z);  o[3] = f2bf(a.w);
        o[4] = f2bf(b4.x); o[5] = f2bf(b4.y); o[6] = f2bf(b4.z); o[7] = f2bf(b4.w);
        *(u16x8*)(dst + off) = o;
    }
}

// ---------- pipelined bf16 MFMA GEMM: C[M,N] = A[M,K]*B[N,K]^T ----------
// BM=256 BN=128 BK=64, 512 thr / 8 waves (4M x 2N, per-wave 64x64).
// 3-buffer LDS, 2 fine phases per K-tile, vmcnt(6) counted waits,
// T2 XOR-chunk swizzle (both-sides involution), T5 setprio, T1 XCD swizzle.
constexpr int BM = 256, BN = 128, BK = 64;
constexpr int A_EL = BM * BK;            // 32 KB
constexpr int B_EL = BN * BK;            // 16 KB
constexpr int BUF_EL = A_EL + B_EL;      // 48 KB x3 = 144 KB

template <bool OUT_BF16, bool SHIFTED>
__global__ __launch_bounds__(512, 2) void gemm_nt_pipe(
    const u16* __restrict__ A, const u16* __restrict__ B,
    void* __restrict__ Cout, int M, int N, int K)
{
    __shared__ u16 lds[3 * BUF_EL];

    const int tid  = threadIdx.x;
    const int lane = tid & 63;
    const int wave = tid >> 6;

    const int nwg = gridDim.x;
    const int bid = blockIdx.x;
    const int swz = (bid & 7) * (nwg >> 3) + (bid >> 3);
    const int ntn = N >> 7;
    const int row0 = (swz / ntn) * BM;
    const int col0 = (swz % ntn) * BN;

    int arow0;
    if (SHIFTED) {
        const int b  = row0 >> 10;            // BM=256 | 1024: no batch straddle
        const int q0 = row0 & (SEQL - 1);
        arow0 = b * VROWS + q0 + 4 + c_ofs[col0 >> 7];
    } else {
        arow0 = row0;
    }
    const u16* Ab = A + (size_t)arow0 * K;
    const u16* Bb = B + (size_t)col0 * K;

    const int wm = wave >> 1;    // 0..3 (M quarter)
    const int wn = wave & 1;     // 0..1 (N half)
    const int fr = lane & 15;
    const int fg = lane >> 4;

    const int srow   = tid >> 3;
    const int schunk = tid & 7;

    f32x4 acc[4][4] = {};
    s16x8 af[4][2], bf0[2][2], bf1[2][2];

    auto stageA3 = [&](int bsel, int kt) {
        u16* Abuf = lds + bsel * BUF_EL;
        const int k0 = kt << 6;
        #pragma unroll
        for (int c = 0; c < 3; ++c) {
            const int row = c * 64 + srow;
            const int sc  = (schunk ^ (row & 7)) << 3;
            GLOAD_LDS16(Ab + (size_t)row * K + k0 + sc, Abuf + c * 4096 + wave * 512);
        }
    };
    auto stageRest = [&](int bsel, int kt) {
        u16* Abuf = lds + bsel * BUF_EL;
        u16* Bbuf = Abuf + A_EL;
        const int k0 = kt << 6;
        {
            const int row = 192 + srow;
            const int sc  = (schunk ^ (row & 7)) << 3;
            GLOAD_LDS16(Ab + (size_t)row * K + k0 + sc, Abuf + 3 * 4096 + wave * 512);
        }
        #pragma unroll
        for (int c = 0; c < 2; ++c) {
            const int row = c * 64 + srow;
            const int sc  = (schunk ^ (row & 7)) << 3;
            GLOAD_LDS16(Bb + (size_t)row * K + k0 + sc, Bbuf + c * 4096 + wave * 512);
        }
    };

    auto phase0 = [&](int tile, bool doStage) {
        const u16* Abuf = lds + (tile % 3) * BUF_EL;
        const u16* Bbuf = Abuf + A_EL;
        #pragma unroll
        for (int m = 0; m < 4; ++m)
            #pragma unroll
            for (int kk = 0; kk < 2; ++kk) {
                const int row = wm * 64 + m * 16 + fr;
                const int ch  = ((kk << 2) + fg) ^ (row & 7);
                af[m][kk] = *(const s16x8*)(Abuf + row * 64 + ch * 8);
            }
        #pragma unroll
        for (int n = 0; n < 2; ++n)
            #pragma unroll
            for (int kk = 0; kk < 2; ++kk) {
                const int row = wn * 64 + n * 16 + fr;
                const int ch  = ((kk << 2) + fg) ^ (row & 7);
                bf0[n][kk] = *(const s16x8*)(Bbuf + row * 64 + ch * 8);
            }
        if (doStage) stageA3((tile + 2) % 3, tile + 2);
        __builtin_amdgcn_s_barrier();
        asm volatile("s_waitcnt lgkmcnt(0)" ::: "memory");
        __builtin_amdgcn_sched_barrier(0);
        __builtin_amdgcn_s_setprio(1);
        #pragma unroll
        for (int m = 0; m < 4; ++m)
            #pragma unroll
            for (int n = 0; n < 2; ++n)
                #pragma unroll
                for (int kk = 0; kk < 2; ++kk)
                    acc[m][n] = __builtin_amdgcn_mfma_f32_16x16x32_bf16(
                        af[m][kk], bf0[n][kk], acc[m][n], 0, 0, 0);
        __builtin_amdgcn_s_setprio(0);
        __builtin_amdgcn_s_barrier();
    };

    auto phase1 = [&](int tile, int mode /*0: stage+vm6, 1: vm0, 2: none*/) {
        const u16* Abuf = lds + (tile % 3) * BUF_EL;
        const u16* Bbuf = Abuf + A_EL;
        #pragma unroll
        for (int n = 0; n < 2; ++n)
            #pragma unroll
            for (int kk = 0; kk < 2; ++kk) {
                const int row = wn * 64 + (2 + n) * 16 + fr;
                const int ch  = ((kk << 2) + fg) ^ (row & 7);
                bf1[n][kk] = *(const s16x8*)(Bbuf + row * 64 + ch * 8);
            }
        if (mode == 0) {
            stageRest((tile + 2) % 3, tile + 2);
            asm volatile("s_waitcnt vmcnt(6)" ::: "memory");
        } else if (mode == 1) {
            asm volatile("s_waitcnt vmcnt(0)" ::: "memory");
        }
        __builtin_amdgcn_s_barrier();
        asm volatile("s_waitcnt lgkmcnt(0)" ::: "memory");
        __builtin_amdgcn_sched_barrier(0);
        __builtin_amdgcn_s_setprio(1);
        #pragma unroll
        for (int m = 0; m < 4; ++m)
            #pragma unroll
            for (int n = 0; n < 2; ++n)
                #pragma unroll
                for (int kk = 0; kk < 2; ++kk)
                    acc[m][2 + n] = __builtin_amdgcn_mfma_f32_16x16x32_bf16(
                        af[m][kk], bf1[n][kk], acc[m][2 + n], 0, 0, 0);
        __builtin_amdgcn_s_setprio(0);
        __builtin_amdgcn_s_barrier();
    };

    const int NT = K >> 6;               // 16

    stageA3(0, 0); stageRest(0, 0);
    stageA3(1, 1); stageRest(1, 1);
    asm volatile("s_waitcnt vmcnt(6)" ::: "memory");
    __builtin_amdgcn_s_barrier();

    for (int t = 0; t < NT - 2; ++t) { phase0(t, true); phase1(t, 0); }
    phase0(NT - 2, false); phase1(NT - 2, 1);
    phase0(NT - 1, false); phase1(NT - 1, 2);

    const int crow0 = row0 + wm * 64 + fg * 4;
    const int ccol0 = col0 + wn * 64 + fr;
    if (OUT_BF16) {
        u16* C = (u16*)Cout;
        #pragma unroll
        for (int m = 0; m < 4; ++m)
            #pragma unroll
            for (int n = 0; n < 4; ++n)
                #pragma unroll
                for (int j = 0; j < 4; ++j)
                    C[(size_t)(crow0 + m * 16 + j) * N + ccol0 + n * 16] =
                        f2bf(acc[m][n][j]);
    } else {
        float* C = (float*)Cout;
        #pragma unroll
        for (int m = 0; m < 4; ++m)
            #pragma unroll
            for (int n = 0; n < 4; ++n)
                #pragma unroll
                for (int j = 0; j < 4; ++j)
                    C[(size_t)(crow0 + m * 16 + j) * N + ccol0 + n * 16] =
                        acc[m][n][j];
    }
}

extern "C" void kernel_launch(void* const* d_in, const int* in_sizes, int n_in,
                              void* d_out, int out_size, void* d_ws, size_t ws_size,
                              hipStream_t stream) {
    const float* values = (const float*)d_in[0];
    // d_in[1] = queries: only its length matters (Lq == L)
    const unsigned char* mask = (const unsigned char*)d_in[2];
    const float* Win  = (const float*)d_in[3];
    const float* Wout = (const float*)d_in[4];
    float* out = (float*)d_out;

    const int M = BATCH * SEQL;   // 8192
    const int N = EMB;            // 1024
    const int K = EMB;            // 1024

    u16* VG    = (u16*)d_ws;                              // 8*1040*1024 (17 MB)
    u16* Attb  = VG + (size_t)BATCH * VROWS * EMB;        // 16 MB
    u16* Winb  = Attb + (size_t)M * EMB;                  // 2 MB
    u16* Woutb = Winb + (size_t)EMB * EMB;                // 2 MB (~37 MB total)

    // 520 smoothing blocks + 1024 weight-cvt blocks
    smooth_cvt<<<1544, 256, 0, stream>>>(values, mask, Win, Wout, VG, Winb, Woutb);

    dim3 ggrid((M / BM) * (N / BN));   // 32*8 = 256 WGs
    gemm_nt_pipe<true,  true ><<<ggrid, 512, 0, stream>>>(VG,   Winb,  Attb, M, N, K);
    gemm_nt_pipe<false, false><<<ggrid, 512, 0, stream>>>(Attb, Woutb, out,  M, N, K);
}

// Round 6
// 84.510 us; speedup vs baseline: 8.5238x; 8.5238x over previous
//
#include <hip/hip_runtime.h>
#include <hip/hip_bf16.h>
#include <cstddef>

// B=8, L=1024, E=1024, H=8, d=128
// out = BandedGaussianAttn(values @ Win^T) @ Wout^T
// Pipeline (all stages individually proven in R2-R4):
//   cvt_all:     values,Win,Wout fp32 -> bf16            (R3, ~10us)
//   GEMM1:       Vb = valb @ Winb^T   bf16->bf16         (R4 2-phase pipe, ~19.5us)
//   banded_attn: Attb = 13-tap per-head-offset stencil   (R3, ~8us)
//   GEMM2:       out = Attb @ Woutb^T bf16->fp32         (R4 2-phase pipe, ~19.5us)

#define BATCH 8
#define SEQL  1024
#define EMB   1024
#define RAD   6

typedef unsigned short u16;
typedef __attribute__((ext_vector_type(8))) short s16x8;
typedef __attribute__((ext_vector_type(4))) float f32x4;
typedef __attribute__((ext_vector_type(8))) unsigned short u16x8;

#define GLOAD_LDS16(g, l)                                                     \
    __builtin_amdgcn_global_load_lds(                                         \
        (const __attribute__((address_space(1))) void*)(g),                   \
        (__attribute__((address_space(3))) void*)(l), 16, 0, 0)

__device__ __forceinline__ u16 f2bf(float f) {
    unsigned u = __builtin_bit_cast(unsigned, f);
    u += 0x7FFF + ((u >> 16) & 1);
    return (u16)(u >> 16);
}
__device__ __forceinline__ float bf2f(u16 h) {
    return __builtin_bit_cast(float, (unsigned)h << 16);
}

__constant__ float c_w[2 * RAD + 1] = {
    6.075882849823286e-09f, 1.4867195147342979e-06f, 1.3383022576488537e-04f,
    4.431848411938008e-03f, 5.399096651318806e-02f,  2.4197072451914337e-01f,
    3.989422804014327e-01f,
    2.4197072451914337e-01f, 5.399096651318806e-02f, 4.431848411938008e-03f,
    1.3383022576488537e-04f, 1.4867195147342979e-06f, 6.075882849823286e-09f
};
__constant__ int c_ofs[8] = { -3, -2, -1, 0, 0, 1, 2, 3 };

// ---------------- merged fp32 -> bf16 convert (proven R3) ----------------
__global__ __launch_bounds__(256) void cvt_all(
    const float* __restrict__ v, const float* __restrict__ wi,
    const float* __restrict__ wo, u16* __restrict__ vb,
    u16* __restrict__ wib, u16* __restrict__ wob)
{
    const int i = blockIdx.x * 256 + threadIdx.x;
    const float* src; u16* dst; size_t off;
    if (i < 1048576)               { src = v;  dst = vb;  off = (size_t)i * 8; }
    else if (i < 1048576 + 131072) { src = wi; dst = wib; off = (size_t)(i - 1048576) * 8; }
    else                           { src = wo; dst = wob; off = (size_t)(i - 1179648) * 8; }
    float4 a = *(const float4*)(src + off);
    float4 b = *(const float4*)(src + off + 4);
    u16x8 o;
    o[0] = f2bf(a.x); o[1] = f2bf(a.y); o[2] = f2bf(a.z); o[3] = f2bf(a.w);
    o[4] = f2bf(b.x); o[5] = f2bf(b.y); o[6] = f2bf(b.z); o[7] = f2bf(b.w);
    *(u16x8*)(dst + off) = o;
}

// ---------------- banded gaussian stencil, bf16->bf16 (proven R3) ----------------
__global__ __launch_bounds__(256) void banded_attn(
    const u16* __restrict__ V, const unsigned char* __restrict__ mask,
    u16* __restrict__ Att)
{
    const int idx = blockIdx.x * 256 + threadIdx.x;  // over B*L*(E/8) = 1M
    const int e   = (idx & 127) * 8;
    const int q   = (idx >> 7) & (SEQL - 1);
    const int b   = idx >> 17;
    const int h   = e >> 7;
    const int vbase = q + c_ofs[h];

    float acc[8] = {};
    #pragma unroll
    for (int j = -RAD; j <= RAD; ++j) {
        const int vp = vbase + j;
        if (vp < 0 || vp >= SEQL) continue;
        if (mask[b * SEQL + vp]) continue;           // masked_fill on v rows
        const float w = c_w[j + RAD];
        const u16x8 v = *(const u16x8*)&V[((size_t)(b * SEQL + vp)) * EMB + e];
        #pragma unroll
        for (int t = 0; t < 8; ++t) acc[t] = fmaf(w, bf2f(v[t]), acc[t]);
    }
    u16x8 o;
    #pragma unroll
    for (int t = 0; t < 8; ++t) o[t] = f2bf(acc[t]);
    *(u16x8*)&Att[((size_t)(b * SEQL + q)) * EMB + e] = o;
}

// ---------- pipelined bf16 MFMA GEMM: C[M,N] = A[M,K]*B[N,K]^T (proven R4) ----------
// BM=256 BN=128 BK=64, 512 thr / 8 waves (4M x 2N, per-wave 64x64).
// 3-buffer LDS, 2 fine phases per K-tile, vmcnt(6) counted waits,
// T2 XOR-chunk swizzle (both-sides involution), T5 setprio, T1 XCD swizzle.
constexpr int BM = 256, BN = 128, BK = 64;
constexpr int A_EL = BM * BK;            // 32 KB
constexpr int B_EL = BN * BK;            // 16 KB
constexpr int BUF_EL = A_EL + B_EL;      // 48 KB x3 = 144 KB

template <bool OUT_BF16>
__global__ __launch_bounds__(512, 2) void gemm_nt_pipe(
    const u16* __restrict__ A, const u16* __restrict__ B,
    void* __restrict__ Cout, int M, int N, int K)
{
    __shared__ u16 lds[3 * BUF_EL];

    const int tid  = threadIdx.x;
    const int lane = tid & 63;
    const int wave = tid >> 6;

    const int nwg = gridDim.x;
    const int bid = blockIdx.x;
    const int swz = (bid & 7) * (nwg >> 3) + (bid >> 3);
    const int ntn = N >> 7;
    const int row0 = (swz / ntn) * BM;
    const int col0 = (swz % ntn) * BN;

    const u16* Ab = A + (size_t)row0 * K;
    const u16* Bb = B + (size_t)col0 * K;

    const int wm = wave >> 1;    // 0..3 (M quarter)
    const int wn = wave & 1;     // 0..1 (N half)
    const int fr = lane & 15;
    const int fg = lane >> 4;

    const int srow   = tid >> 3;
    const int schunk = tid & 7;

    f32x4 acc[4][4] = {};
    s16x8 af[4][2], bf0[2][2], bf1[2][2];

    auto stageA3 = [&](int bsel, int kt) {
        u16* Abuf = lds + bsel * BUF_EL;
        const int k0 = kt << 6;
        #pragma unroll
        for (int c = 0; c < 3; ++c) {
            const int row = c * 64 + srow;
            const int sc  = (schunk ^ (row & 7)) << 3;
            GLOAD_LDS16(Ab + (size_t)row * K + k0 + sc, Abuf + c * 4096 + wave * 512);
        }
    };
    auto stageRest = [&](int bsel, int kt) {
        u16* Abuf = lds + bsel * BUF_EL;
        u16* Bbuf = Abuf + A_EL;
        const int k0 = kt << 6;
        {
            const int row = 192 + srow;
            const int sc  = (schunk ^ (row & 7)) << 3;
            GLOAD_LDS16(Ab + (size_t)row * K + k0 + sc, Abuf + 3 * 4096 + wave * 512);
        }
        #pragma unroll
        for (int c = 0; c < 2; ++c) {
            const int row = c * 64 + srow;
            const int sc  = (schunk ^ (row & 7)) << 3;
            GLOAD_LDS16(Bb + (size_t)row * K + k0 + sc, Bbuf + c * 4096 + wave * 512);
        }
    };

    auto phase0 = [&](int tile, bool doStage) {
        const u16* Abuf = lds + (tile % 3) * BUF_EL;
        const u16* Bbuf = Abuf + A_EL;
        #pragma unroll
        for (int m = 0; m < 4; ++m)
            #pragma unroll
            for (int kk = 0; kk < 2; ++kk) {
                const int row = wm * 64 + m * 16 + fr;
                const int ch  = ((kk << 2) + fg) ^ (row & 7);
                af[m][kk] = *(const s16x8*)(Abuf + row * 64 + ch * 8);
            }
        #pragma unroll
        for (int n = 0; n < 2; ++n)
            #pragma unroll
            for (int kk = 0; kk < 2; ++kk) {
                const int row = wn * 64 + n * 16 + fr;
                const int ch  = ((kk << 2) + fg) ^ (row & 7);
                bf0[n][kk] = *(const s16x8*)(Bbuf + row * 64 + ch * 8);
            }
        if (doStage) stageA3((tile + 2) % 3, tile + 2);
        __builtin_amdgcn_s_barrier();
        asm volatile("s_waitcnt lgkmcnt(0)" ::: "memory");
        __builtin_amdgcn_sched_barrier(0);
        __builtin_amdgcn_s_setprio(1);
        #pragma unroll
        for (int m = 0; m < 4; ++m)
            #pragma unroll
            for (int n = 0; n < 2; ++n)
                #pragma unroll
                for (int kk = 0; kk < 2; ++kk)
                    acc[m][n] = __builtin_amdgcn_mfma_f32_16x16x32_bf16(
                        af[m][kk], bf0[n][kk], acc[m][n], 0, 0, 0);
        __builtin_amdgcn_s_setprio(0);
        __builtin_amdgcn_s_barrier();
    };

    auto phase1 = [&](int tile, int mode /*0: stage+vm6, 1: vm0, 2: none*/) {
        const u16* Abuf = lds + (tile % 3) * BUF_EL;
        const u16* Bbuf = Abuf + A_EL;
        #pragma unroll
        for (int n = 0; n < 2; ++n)
            #pragma unroll
            for (int kk = 0; kk < 2; ++kk) {
                const int row = wn * 64 + (2 + n) * 16 + fr;
                const int ch  = ((kk << 2) + fg) ^ (row & 7);
                bf1[n][kk] = *(const s16x8*)(Bbuf + row * 64 + ch * 8);
            }
        if (mode == 0) {
            stageRest((tile + 2) % 3, tile + 2);
            asm volatile("s_waitcnt vmcnt(6)" ::: "memory");
        } else if (mode == 1) {
            asm volatile("s_waitcnt vmcnt(0)" ::: "memory");
        }
        __builtin_amdgcn_s_barrier();
        asm volatile("s_waitcnt lgkmcnt(0)" ::: "memory");
        __builtin_amdgcn_sched_barrier(0);
        __builtin_amdgcn_s_setprio(1);
        #pragma unroll
        for (int m = 0; m < 4; ++m)
            #pragma unroll
            for (int n = 0; n < 2; ++n)
                #pragma unroll
                for (int kk = 0; kk < 2; ++kk)
                    acc[m][2 + n] = __builtin_amdgcn_mfma_f32_16x16x32_bf16(
                        af[m][kk], bf1[n][kk], acc[m][2 + n], 0, 0, 0);
        __builtin_amdgcn_s_setprio(0);
        __builtin_amdgcn_s_barrier();
    };

    const int NT = K >> 6;               // 16

    stageA3(0, 0); stageRest(0, 0);
    stageA3(1, 1); stageRest(1, 1);
    asm volatile("s_waitcnt vmcnt(6)" ::: "memory");
    __builtin_amdgcn_s_barrier();

    for (int t = 0; t < NT - 2; ++t) { phase0(t, true); phase1(t, 0); }
    phase0(NT - 2, false); phase1(NT - 2, 1);
    phase0(NT - 1, false); phase1(NT - 1, 2);

    const int crow0 = row0 + wm * 64 + fg * 4;
    const int ccol0 = col0 + wn * 64 + fr;
    if (OUT_BF16) {
        u16* C = (u16*)Cout;
        #pragma unroll
        for (int m = 0; m < 4; ++m)
            #pragma unroll
            for (int n = 0; n < 4; ++n)
                #pragma unroll
                for (int j = 0; j < 4; ++j)
                    C[(size_t)(crow0 + m * 16 + j) * N + ccol0 + n * 16] =
                        f2bf(acc[m][n][j]);
    } else {
        float* C = (float*)Cout;
        #pragma unroll
        for (int m = 0; m < 4; ++m)
            #pragma unroll
            for (int n = 0; n < 4; ++n)
                #pragma unroll
                for (int j = 0; j < 4; ++j)
                    C[(size_t)(crow0 + m * 16 + j) * N + ccol0 + n * 16] =
                        acc[m][n][j];
    }
}

extern "C" void kernel_launch(void* const* d_in, const int* in_sizes, int n_in,
                              void* d_out, int out_size, void* d_ws, size_t ws_size,
                              hipStream_t stream) {
    const float* values = (const float*)d_in[0];
    // d_in[1] = queries: only its length matters (Lq == L)
    const unsigned char* mask = (const unsigned char*)d_in[2];
    const float* Win  = (const float*)d_in[3];
    const float* Wout = (const float*)d_in[4];
    float* out = (float*)d_out;

    const int M = BATCH * SEQL;   // 8192
    const int N = EMB;            // 1024
    const int K = EMB;            // 1024
    const size_t ME = (size_t)M * EMB;     // 8M elems
    const size_t WE = (size_t)EMB * EMB;   // 1M elems

    u16* valb  = (u16*)d_ws;          // 16 MB
    u16* Vb    = valb + ME;           // 16 MB
    u16* Attb  = Vb + ME;             // 16 MB
    u16* Winb  = Attb + ME;           // 2 MB
    u16* Woutb = Winb + WE;           // 2 MB  (52 MB total)

    cvt_all<<<5120, 256, 0, stream>>>(values, Win, Wout, valb, Winb, Woutb);

    dim3 ggrid((M / BM) * (N / BN));   // 256 WGs
    gemm_nt_pipe<true><<<ggrid, 512, 0, stream>>>(valb, Winb, Vb, M, N, K);

    banded_attn<<<(int)(ME / 8 / 256), 256, 0, stream>>>(Vb, mask, Attb);

    gemm_nt_pipe<false><<<ggrid, 512, 0, stream>>>(Attb, Woutb, out, M, N, K);
}

// Round 7
// 83.026 us; speedup vs baseline: 8.6761x; 1.0179x over previous
//
#include <hip/hip_runtime.h>
#include <hip/hip_bf16.h>
#include <cstddef>

// B=8, L=1024, E=1024, H=8, d=128
// out = BandedGaussianAttn(values @ Win^T) @ Wout^T
// Identity (R4-proven): smoothing (equal stds) commutes with the projection,
// and the per-head offset becomes a row shift of GEMM1's A operand selected
// by the output column block (BN=128 == one head).
// Pipeline (3 kernels):
//   smooth_cvt: LDS-strip 13-tap smoothing fp32->bf16 (+ weight cvt)
//   GEMM1:      Attb = VG(shifted rows) @ Winb^T   bf16->bf16
//   GEMM2:      out  = Attb @ Woutb^T              bf16->fp32

#define BATCH 8
#define SEQL  1024
#define EMB   1024
#define VROWS 1032            // VG row r holds smoothed source row p = r-4
#define RSTRIP 24             // output rows per strip block
#define NSTRIPS 43            // 43*24 = 1032
#define INROWS (RSTRIP + 12)  // 36 input rows incl. 2*RAD halo

typedef unsigned short u16;
typedef __attribute__((ext_vector_type(8))) short s16x8;
typedef __attribute__((ext_vector_type(4))) float f32x4;
typedef __attribute__((ext_vector_type(8))) unsigned short u16x8;
typedef __attribute__((ext_vector_type(4))) unsigned short u16x4;

#define GLOAD_LDS16(g, l)                                                     \
    __builtin_amdgcn_global_load_lds(                                         \
        (const __attribute__((address_space(1))) void*)(g),                   \
        (__attribute__((address_space(3))) void*)(l), 16, 0, 0)

__device__ __forceinline__ u16 f2bf(float f) {
    unsigned u = __builtin_bit_cast(unsigned, f);
    u += 0x7FFF + ((u >> 16) & 1);
    return (u16)(u >> 16);
}
__device__ __forceinline__ float bf2f(u16 h) {
    return __builtin_bit_cast(float, (unsigned)h << 16);
}

__constant__ float c_w[13] = {
    6.075882849823286e-09f, 1.4867195147342979e-06f, 1.3383022576488537e-04f,
    4.431848411938008e-03f, 5.399096651318806e-02f,  2.4197072451914337e-01f,
    3.989422804014327e-01f,
    2.4197072451914337e-01f, 5.399096651318806e-02f, 4.431848411938008e-03f,
    1.3383022576488537e-04f, 1.4867195147342979e-06f, 6.075882849823286e-09f
};
__constant__ int c_ofs[8] = { -3, -2, -1, 0, 0, 1, 2, 3 };

// ---------- smooth_cvt: LDS-strip smoothing + weight cvt ----------
// blocks [0,344): strip smoothing. b = blk&7, s = blk>>3 (strip).
//   load 36 input rows once (bf16 into LDS), compute 24 output rows each
//   with only 4 live fp32 accumulators (sequential r -> no spill).
// blocks [344,1368): fp32->bf16 cvt of Win/Wout.
__global__ __launch_bounds__(256) void smooth_cvt(
    const float* __restrict__ values, const unsigned char* __restrict__ mask,
    const float* __restrict__ wi, const float* __restrict__ wo,
    u16* __restrict__ VG, u16* __restrict__ wib, u16* __restrict__ wob)
{
    const int blk = blockIdx.x;
    if (blk < BATCH * NSTRIPS) {
        __shared__ u16 sm[INROWS][EMB];          // 72 KB
        const int b  = blk & 7;
        const int s  = blk >> 3;                 // 0..42
        const int r0 = s * RSTRIP;               // first output VG row
        const int v0 = r0 - 10;                  // first input row (p0 - RAD, p0=r0-4)
        const int tid = threadIdx.x;
        const float* vb = values + (size_t)b * SEQL * EMB;
        const unsigned char* mrow = mask + b * SEQL;

        for (int i = 0; i < INROWS * 256; i += 256) {
            const int gidx = i + tid;
            const int row  = gidx >> 8;          // 0..35
            const int c4   = (gidx & 255) * 4;
            const int v    = v0 + row;
            u16x4 o;
            if (v >= 0 && v < SEQL && !mrow[v]) {
                const float4 x = *(const float4*)(vb + (size_t)v * EMB + c4);
                o[0] = f2bf(x.x); o[1] = f2bf(x.y);
                o[2] = f2bf(x.z); o[3] = f2bf(x.w);
            } else {
                o[0] = 0; o[1] = 0; o[2] = 0; o[3] = 0;   // OOB or masked row
            }
            *(u16x4*)&sm[row][c4] = o;
        }
        __syncthreads();

        const int c = tid * 4;
        u16* og = VG + (size_t)(b * VROWS + r0) * EMB + c;
        for (int r = 0; r < RSTRIP; ++r) {
            float a0 = 0.f, a1 = 0.f, a2 = 0.f, a3 = 0.f;
            #pragma unroll
            for (int jj = 0; jj < 13; ++jj) {
                const float w = c_w[jj];
                const u16x4 x = *(const u16x4*)&sm[r + jj][c];
                a0 = fmaf(w, bf2f(x[0]), a0);
                a1 = fmaf(w, bf2f(x[1]), a1);
                a2 = fmaf(w, bf2f(x[2]), a2);
                a3 = fmaf(w, bf2f(x[3]), a3);
            }
            u16x4 o;
            o[0] = f2bf(a0); o[1] = f2bf(a1); o[2] = f2bf(a2); o[3] = f2bf(a3);
            *(u16x4*)(og + (size_t)r * EMB) = o;
        }
    } else {
        const int k = (blk - BATCH * NSTRIPS) * 256 + threadIdx.x;  // 0..262143
        const float* src = (k < 131072) ? wi : wo;
        u16* dst = (k < 131072) ? wib : wob;
        const size_t off = (size_t)(k & 131071) * 8;
        const float4 a = *(const float4*)(src + off);
        const float4 b4 = *(const float4*)(src + off + 4);
        u16x8 o;
        o[0] = f2bf(a.x);  o[1] = f2bf(a.y);  o[2] = f2bf(a.z);  o[3] = f2bf(a.w);
        o[4] = f2bf(b4.x); o[5] = f2bf(b4.y); o[6] = f2bf(b4.z); o[7] = f2bf(b4.w);
        *(u16x8*)(dst + off) = o;
    }
}

// ---------- pipelined bf16 MFMA GEMM: C[M,N] = A[M,K]*B[N,K]^T (R4/R6-proven) ----------
// BM=256 BN=128 BK=64, 512 thr / 8 waves (4M x 2N, per-wave 64x64).
// 3-buffer LDS, 2 fine phases per K-tile, vmcnt(6) counted waits,
// T2 XOR-chunk swizzle, T5 setprio, T1 XCD swizzle.
constexpr int BM = 256, BN = 128, BK = 64;
constexpr int A_EL = BM * BK;
constexpr int B_EL = BN * BK;
constexpr int BUF_EL = A_EL + B_EL;      // 48 KB x3 = 144 KB

template <bool OUT_BF16, bool SHIFTED>
__global__ __launch_bounds__(512, 2) void gemm_nt_pipe(
    const u16* __restrict__ A, const u16* __restrict__ B,
    void* __restrict__ Cout, int M, int N, int K)
{
    __shared__ u16 lds[3 * BUF_EL];

    const int tid  = threadIdx.x;
    const int lane = tid & 63;
    const int wave = tid >> 6;

    const int nwg = gridDim.x;
    const int bid = blockIdx.x;
    const int swz = (bid & 7) * (nwg >> 3) + (bid >> 3);
    const int ntn = N >> 7;
    const int row0 = (swz / ntn) * BM;
    const int col0 = (swz % ntn) * BN;

    int arow0;
    if (SHIFTED) {
        const int b  = row0 >> 10;            // BM=256 | 1024: no batch straddle
        const int q0 = row0 & (SEQL - 1);
        arow0 = b * VROWS + q0 + 4 + c_ofs[col0 >> 7];
    } else {
        arow0 = row0;
    }
    const u16* Ab = A + (size_t)arow0 * K;
    const u16* Bb = B + (size_t)col0 * K;

    const int wm = wave >> 1;
    const int wn = wave & 1;
    const int fr = lane & 15;
    const int fg = lane >> 4;

    const int srow   = tid >> 3;
    const int schunk = tid & 7;

    f32x4 acc[4][4] = {};
    s16x8 af[4][2], bf0[2][2], bf1[2][2];

    auto stageA3 = [&](int bsel, int kt) {
        u16* Abuf = lds + bsel * BUF_EL;
        const int k0 = kt << 6;
        #pragma unroll
        for (int c = 0; c < 3; ++c) {
            const int row = c * 64 + srow;
            const int sc  = (schunk ^ (row & 7)) << 3;
            GLOAD_LDS16(Ab + (size_t)row * K + k0 + sc, Abuf + c * 4096 + wave * 512);
        }
    };
    auto stageRest = [&](int bsel, int kt) {
        u16* Abuf = lds + bsel * BUF_EL;
        u16* Bbuf = Abuf + A_EL;
        const int k0 = kt << 6;
        {
            const int row = 192 + srow;
            const int sc  = (schunk ^ (row & 7)) << 3;
            GLOAD_LDS16(Ab + (size_t)row * K + k0 + sc, Abuf + 3 * 4096 + wave * 512);
        }
        #pragma unroll
        for (int c = 0; c < 2; ++c) {
            const int row = c * 64 + srow;
            const int sc  = (schunk ^ (row & 7)) << 3;
            GLOAD_LDS16(Bb + (size_t)row * K + k0 + sc, Bbuf + c * 4096 + wave * 512);
        }
    };

    auto phase0 = [&](int tile, bool doStage) {
        const u16* Abuf = lds + (tile % 3) * BUF_EL;
        const u16* Bbuf = Abuf + A_EL;
        #pragma unroll
        for (int m = 0; m < 4; ++m)
            #pragma unroll
            for (int kk = 0; kk < 2; ++kk) {
                const int row = wm * 64 + m * 16 + fr;
                const int ch  = ((kk << 2) + fg) ^ (row & 7);
                af[m][kk] = *(const s16x8*)(Abuf + row * 64 + ch * 8);
            }
        #pragma unroll
        for (int n = 0; n < 2; ++n)
            #pragma unroll
            for (int kk = 0; kk < 2; ++kk) {
                const int row = wn * 64 + n * 16 + fr;
                const int ch  = ((kk << 2) + fg) ^ (row & 7);
                bf0[n][kk] = *(const s16x8*)(Bbuf + row * 64 + ch * 8);
            }
        if (doStage) stageA3((tile + 2) % 3, tile + 2);
        __builtin_amdgcn_s_barrier();
        asm volatile("s_waitcnt lgkmcnt(0)" ::: "memory");
        __builtin_amdgcn_sched_barrier(0);
        __builtin_amdgcn_s_setprio(1);
        #pragma unroll
        for (int m = 0; m < 4; ++m)
            #pragma unroll
            for (int n = 0; n < 2; ++n)
                #pragma unroll
                for (int kk = 0; kk < 2; ++kk)
                    acc[m][n] = __builtin_amdgcn_mfma_f32_16x16x32_bf16(
                        af[m][kk], bf0[n][kk], acc[m][n], 0, 0, 0);
        __builtin_amdgcn_s_setprio(0);
        __builtin_amdgcn_s_barrier();
    };

    auto phase1 = [&](int tile, int mode /*0: stage+vm6, 1: vm0, 2: none*/) {
        const u16* Abuf = lds + (tile % 3) * BUF_EL;
        const u16* Bbuf = Abuf + A_EL;
        #pragma unroll
        for (int n = 0; n < 2; ++n)
            #pragma unroll
            for (int kk = 0; kk < 2; ++kk) {
                const int row = wn * 64 + (2 + n) * 16 + fr;
                const int ch  = ((kk << 2) + fg) ^ (row & 7);
                bf1[n][kk] = *(const s16x8*)(Bbuf + row * 64 + ch * 8);
            }
        if (mode == 0) {
            stageRest((tile + 2) % 3, tile + 2);
            asm volatile("s_waitcnt vmcnt(6)" ::: "memory");
        } else if (mode == 1) {
            asm volatile("s_waitcnt vmcnt(0)" ::: "memory");
        }
        __builtin_amdgcn_s_barrier();
        asm volatile("s_waitcnt lgkmcnt(0)" ::: "memory");
        __builtin_amdgcn_sched_barrier(0);
        __builtin_amdgcn_s_setprio(1);
        #pragma unroll
        for (int m = 0; m < 4; ++m)
            #pragma unroll
            for (int n = 0; n < 2; ++n)
                #pragma unroll
                for (int kk = 0; kk < 2; ++kk)
                    acc[m][2 + n] = __builtin_amdgcn_mfma_f32_16x16x32_bf16(
                        af[m][kk], bf1[n][kk], acc[m][2 + n], 0, 0, 0);
        __builtin_amdgcn_s_setprio(0);
        __builtin_amdgcn_s_barrier();
    };

    const int NT = K >> 6;

    stageA3(0, 0); stageRest(0, 0);
    stageA3(1, 1); stageRest(1, 1);
    asm volatile("s_waitcnt vmcnt(6)" ::: "memory");
    __builtin_amdgcn_s_barrier();

    for (int t = 0; t < NT - 2; ++t) { phase0(t, true); phase1(t, 0); }
    phase0(NT - 2, false); phase1(NT - 2, 1);
    phase0(NT - 1, false); phase1(NT - 1, 2);

    const int crow0 = row0 + wm * 64 + fg * 4;
    const int ccol0 = col0 + wn * 64 + fr;
    if (OUT_BF16) {
        u16* C = (u16*)Cout;
        #pragma unroll
        for (int m = 0; m < 4; ++m)
            #pragma unroll
            for (int n = 0; n < 4; ++n)
                #pragma unroll
                for (int j = 0; j < 4; ++j)
                    C[(size_t)(crow0 + m * 16 + j) * N + ccol0 + n * 16] =
                        f2bf(acc[m][n][j]);
    } else {
        float* C = (float*)Cout;
        #pragma unroll
        for (int m = 0; m < 4; ++m)
            #pragma unroll
            for (int n = 0; n < 4; ++n)
                #pragma unroll
                for (int j = 0; j < 4; ++j)
                    C[(size_t)(crow0 + m * 16 + j) * N + ccol0 + n * 16] =
                        acc[m][n][j];
    }
}

extern "C" void kernel_launch(void* const* d_in, const int* in_sizes, int n_in,
                              void* d_out, int out_size, void* d_ws, size_t ws_size,
                              hipStream_t stream) {
    const float* values = (const float*)d_in[0];
    // d_in[1] = queries: only its length matters (Lq == L)
    const unsigned char* mask = (const unsigned char*)d_in[2];
    const float* Win  = (const float*)d_in[3];
    const float* Wout = (const float*)d_in[4];
    float* out = (float*)d_out;

    const int M = BATCH * SEQL;   // 8192
    const int N = EMB;            // 1024
    const int K = EMB;            // 1024

    u16* VG    = (u16*)d_ws;                              // 8*1032*1024 (16.9 MB)
    u16* Attb  = VG + (size_t)BATCH * VROWS * EMB;        // 16 MB
    u16* Winb  = Attb + (size_t)M * EMB;                  // 2 MB
    u16* Woutb = Winb + (size_t)EMB * EMB;                // 2 MB (~37 MB total)

    // 344 strip blocks + 1024 weight-cvt blocks
    smooth_cvt<<<BATCH * NSTRIPS + 1024, 256, 0, stream>>>(
        values, mask, Win, Wout, VG, Winb, Woutb);

    dim3 ggrid((M / BM) * (N / BN));   // 256 WGs
    gemm_nt_pipe<true,  true ><<<ggrid, 512, 0, stream>>>(VG,   Winb,  Attb, M, N, K);
    gemm_nt_pipe<false, false><<<ggrid, 512, 0, stream>>>(Attb, Woutb, out,  M, N, K);
}

// Round 8
// 75.715 us; speedup vs baseline: 9.5139x; 1.0966x over previous
//
#include <hip/hip_runtime.h>
#include <hip/hip_bf16.h>
#include <cstddef>

// B=8, L=1024, E=1024, H=8, d=128
// out = BandedGaussianAttn(values @ Win^T) @ Wout^T
// Identity (R4/R7-proven): equal stds -> smoothing commutes with projection;
// per-head offset = row shift of GEMM1's A operand (BN=128 == one head).
// Pipeline (3 kernels):
//   smooth_direct: VG[b,r,:] = bf16(sum_j w[j]*values[b,r-4+j,:])  fp32->bf16,
//                  per-thread 13-tap (spill-safe, R4-proven), XCD-local rows
//                  (+ weight cvt in tail blocks)
//   GEMM1: Attb = VG(shifted rows) @ Winb^T   bf16->bf16   (R7-proven)
//   GEMM2: out  = Attb @ Woutb^T              bf16->fp32   (R7-proven)

#define BATCH 8
#define SEQL  1024
#define EMB   1024
#define VROWS 1032   // VG row r holds smoothed source row p = r-4

typedef unsigned short u16;
typedef __attribute__((ext_vector_type(8))) short s16x8;
typedef __attribute__((ext_vector_type(4))) float f32x4;
typedef __attribute__((ext_vector_type(8))) unsigned short u16x8;
typedef __attribute__((ext_vector_type(4))) unsigned short u16x4;

#define GLOAD_LDS16(g, l)                                                     \
    __builtin_amdgcn_global_load_lds(                                         \
        (const __attribute__((address_space(1))) void*)(g),                   \
        (__attribute__((address_space(3))) void*)(l), 16, 0, 0)

__device__ __forceinline__ u16 f2bf(float f) {
    unsigned u = __builtin_bit_cast(unsigned, f);
    u += 0x7FFF + ((u >> 16) & 1);
    return (u16)(u >> 16);
}

__constant__ float c_w[13] = {
    6.075882849823286e-09f, 1.4867195147342979e-06f, 1.3383022576488537e-04f,
    4.431848411938008e-03f, 5.399096651318806e-02f,  2.4197072451914337e-01f,
    3.989422804014327e-01f,
    2.4197072451914337e-01f, 5.399096651318806e-02f, 4.431848411938008e-03f,
    1.3383022576488537e-04f, 1.4867195147342979e-06f, 6.075882849823286e-09f
};
__constant__ int c_ofs[8] = { -3, -2, -1, 0, 0, 1, 2, 3 };

// ---------- smooth_direct: fused 13-tap smoothing fp32->bf16 + weight cvt ----------
// blocks [0, 8256): one VG output row each. b = blk&7 (round-robin dispatch
//   puts batch b on XCD b -> 13-row tap window stays in that XCD's 4MB L2),
//   r = blk>>3 in [0,1032). Thread: one float4 column chunk, 4 accumulators.
// blocks [8256, 9280): fp32->bf16 cvt of Win/Wout.
__global__ __launch_bounds__(256) void smooth_direct(
    const float* __restrict__ values, const unsigned char* __restrict__ mask,
    const float* __restrict__ wi, const float* __restrict__ wo,
    u16* __restrict__ VG, u16* __restrict__ wib, u16* __restrict__ wob)
{
    const int blk = blockIdx.x;
    if (blk < BATCH * VROWS) {
        const int b = blk & 7;
        const int r = blk >> 3;              // VG row, source row p = r-4
        const int c = threadIdx.x * 4;
        const float* vb = values + (size_t)b * SEQL * EMB + c;
        const unsigned char* mrow = mask + b * SEQL;

        float a0 = 0.f, a1 = 0.f, a2 = 0.f, a3 = 0.f;
        #pragma unroll
        for (int j = 0; j < 13; ++j) {
            const int v = r - 10 + j;        // p - 6 + j
            if (v < 0 || v >= SEQL) continue;
            if (mrow[v]) continue;           // masked_fill on v rows
            const float w = c_w[j];
            const float4 x = *(const float4*)(vb + (size_t)v * EMB);
            a0 = fmaf(w, x.x, a0); a1 = fmaf(w, x.y, a1);
            a2 = fmaf(w, x.z, a2); a3 = fmaf(w, x.w, a3);
        }
        u16x4 o;
        o[0] = f2bf(a0); o[1] = f2bf(a1); o[2] = f2bf(a2); o[3] = f2bf(a3);
        *(u16x4*)&VG[(size_t)(b * VROWS + r) * EMB + c] = o;
    } else {
        const int k = (blk - BATCH * VROWS) * 256 + threadIdx.x;  // 0..262143
        const float* src = (k < 131072) ? wi : wo;
        u16* dst = (k < 131072) ? wib : wob;
        const size_t off = (size_t)(k & 131071) * 8;
        const float4 a = *(const float4*)(src + off);
        const float4 b4 = *(const float4*)(src + off + 4);
        u16x8 o;
        o[0] = f2bf(a.x);  o[1] = f2bf(a.y);  o[2] = f2bf(a.z);  o[3] = f2bf(a.w);
        o[4] = f2bf(b4.x); o[5] = f2bf(b4.y); o[6] = f2bf(b4.z); o[7] = f2bf(b4.w);
        *(u16x8*)(dst + off) = o;
    }
}

// ---------- pipelined bf16 MFMA GEMM: C[M,N] = A[M,K]*B[N,K]^T (R7-proven) ----------
// BM=256 BN=128 BK=64, 512 thr / 8 waves (4M x 2N, per-wave 64x64).
// 3-buffer LDS, 2 fine phases per K-tile, vmcnt(6) counted waits,
// T2 XOR-chunk swizzle, T5 setprio, T1 XCD swizzle.
constexpr int BM = 256, BN = 128, BK = 64;
constexpr int A_EL = BM * BK;
constexpr int B_EL = BN * BK;
constexpr int BUF_EL = A_EL + B_EL;      // 48 KB x3 = 144 KB

template <bool OUT_BF16, bool SHIFTED>
__global__ __launch_bounds__(512, 2) void gemm_nt_pipe(
    const u16* __restrict__ A, const u16* __restrict__ B,
    void* __restrict__ Cout, int M, int N, int K)
{
    __shared__ u16 lds[3 * BUF_EL];

    const int tid  = threadIdx.x;
    const int lane = tid & 63;
    const int wave = tid >> 6;

    const int nwg = gridDim.x;
    const int bid = blockIdx.x;
    const int swz = (bid & 7) * (nwg >> 3) + (bid >> 3);
    const int ntn = N >> 7;
    const int row0 = (swz / ntn) * BM;
    const int col0 = (swz % ntn) * BN;

    int arow0;
    if (SHIFTED) {
        const int b  = row0 >> 10;            // BM=256 | 1024: no batch straddle
        const int q0 = row0 & (SEQL - 1);
        arow0 = b * VROWS + q0 + 4 + c_ofs[col0 >> 7];
    } else {
        arow0 = row0;
    }
    const u16* Ab = A + (size_t)arow0 * K;
    const u16* Bb = B + (size_t)col0 * K;

    const int wm = wave >> 1;
    const int wn = wave & 1;
    const int fr = lane & 15;
    const int fg = lane >> 4;

    const int srow   = tid >> 3;
    const int schunk = tid & 7;

    f32x4 acc[4][4] = {};
    s16x8 af[4][2], bf0[2][2], bf1[2][2];

    auto stageA3 = [&](int bsel, int kt) {
        u16* Abuf = lds + bsel * BUF_EL;
        const int k0 = kt << 6;
        #pragma unroll
        for (int c = 0; c < 3; ++c) {
            const int row = c * 64 + srow;
            const int sc  = (schunk ^ (row & 7)) << 3;
            GLOAD_LDS16(Ab + (size_t)row * K + k0 + sc, Abuf + c * 4096 + wave * 512);
        }
    };
    auto stageRest = [&](int bsel, int kt) {
        u16* Abuf = lds + bsel * BUF_EL;
        u16* Bbuf = Abuf + A_EL;
        const int k0 = kt << 6;
        {
            const int row = 192 + srow;
            const int sc  = (schunk ^ (row & 7)) << 3;
            GLOAD_LDS16(Ab + (size_t)row * K + k0 + sc, Abuf + 3 * 4096 + wave * 512);
        }
        #pragma unroll
        for (int c = 0; c < 2; ++c) {
            const int row = c * 64 + srow;
            const int sc  = (schunk ^ (row & 7)) << 3;
            GLOAD_LDS16(Bb + (size_t)row * K + k0 + sc, Bbuf + c * 4096 + wave * 512);
        }
    };

    auto phase0 = [&](int tile, bool doStage) {
        const u16* Abuf = lds + (tile % 3) * BUF_EL;
        const u16* Bbuf = Abuf + A_EL;
        #pragma unroll
        for (int m = 0; m < 4; ++m)
            #pragma unroll
            for (int kk = 0; kk < 2; ++kk) {
                const int row = wm * 64 + m * 16 + fr;
                const int ch  = ((kk << 2) + fg) ^ (row & 7);
                af[m][kk] = *(const s16x8*)(Abuf + row * 64 + ch * 8);
            }
        #pragma unroll
        for (int n = 0; n < 2; ++n)
            #pragma unroll
            for (int kk = 0; kk < 2; ++kk) {
                const int row = wn * 64 + n * 16 + fr;
                const int ch  = ((kk << 2) + fg) ^ (row & 7);
                bf0[n][kk] = *(const s16x8*)(Bbuf + row * 64 + ch * 8);
            }
        if (doStage) stageA3((tile + 2) % 3, tile + 2);
        __builtin_amdgcn_s_barrier();
        asm volatile("s_waitcnt lgkmcnt(0)" ::: "memory");
        __builtin_amdgcn_sched_barrier(0);
        __builtin_amdgcn_s_setprio(1);
        #pragma unroll
        for (int m = 0; m < 4; ++m)
            #pragma unroll
            for (int n = 0; n < 2; ++n)
                #pragma unroll
                for (int kk = 0; kk < 2; ++kk)
                    acc[m][n] = __builtin_amdgcn_mfma_f32_16x16x32_bf16(
                        af[m][kk], bf0[n][kk], acc[m][n], 0, 0, 0);
        __builtin_amdgcn_s_setprio(0);
        __builtin_amdgcn_s_barrier();
    };

    auto phase1 = [&](int tile, int mode /*0: stage+vm6, 1: vm0, 2: none*/) {
        const u16* Abuf = lds + (tile % 3) * BUF_EL;
        const u16* Bbuf = Abuf + A_EL;
        #pragma unroll
        for (int n = 0; n < 2; ++n)
            #pragma unroll
            for (int kk = 0; kk < 2; ++kk) {
                const int row = wn * 64 + (2 + n) * 16 + fr;
                const int ch  = ((kk << 2) + fg) ^ (row & 7);
                bf1[n][kk] = *(const s16x8*)(Bbuf + row * 64 + ch * 8);
            }
        if (mode == 0) {
            stageRest((tile + 2) % 3, tile + 2);
            asm volatile("s_waitcnt vmcnt(6)" ::: "memory");
        } else if (mode == 1) {
            asm volatile("s_waitcnt vmcnt(0)" ::: "memory");
        }
        __builtin_amdgcn_s_barrier();
        asm volatile("s_waitcnt lgkmcnt(0)" ::: "memory");
        __builtin_amdgcn_sched_barrier(0);
        __builtin_amdgcn_s_setprio(1);
        #pragma unroll
        for (int m = 0; m < 4; ++m)
            #pragma unroll
            for (int n = 0; n < 2; ++n)
                #pragma unroll
                for (int kk = 0; kk < 2; ++kk)
                    acc[m][2 + n] = __builtin_amdgcn_mfma_f32_16x16x32_bf16(
                        af[m][kk], bf1[n][kk], acc[m][2 + n], 0, 0, 0);
        __builtin_amdgcn_s_setprio(0);
        __builtin_amdgcn_s_barrier();
    };

    const int NT = K >> 6;

    stageA3(0, 0); stageRest(0, 0);
    stageA3(1, 1); stageRest(1, 1);
    asm volatile("s_waitcnt vmcnt(6)" ::: "memory");
    __builtin_amdgcn_s_barrier();

    for (int t = 0; t < NT - 2; ++t) { phase0(t, true); phase1(t, 0); }
    phase0(NT - 2, false); phase1(NT - 2, 1);
    phase0(NT - 1, false); phase1(NT - 1, 2);

    const int crow0 = row0 + wm * 64 + fg * 4;
    const int ccol0 = col0 + wn * 64 + fr;
    if (OUT_BF16) {
        u16* C = (u16*)Cout;
        #pragma unroll
        for (int m = 0; m < 4; ++m)
            #pragma unroll
            for (int n = 0; n < 4; ++n)
                #pragma unroll
                for (int j = 0; j < 4; ++j)
                    C[(size_t)(crow0 + m * 16 + j) * N + ccol0 + n * 16] =
                        f2bf(acc[m][n][j]);
    } else {
        float* C = (float*)Cout;
        #pragma unroll
        for (int m = 0; m < 4; ++m)
            #pragma unroll
            for (int n = 0; n < 4; ++n)
                #pragma unroll
                for (int j = 0; j < 4; ++j)
                    C[(size_t)(crow0 + m * 16 + j) * N + ccol0 + n * 16] =
                        acc[m][n][j];
    }
}

extern "C" void kernel_launch(void* const* d_in, const int* in_sizes, int n_in,
                              void* d_out, int out_size, void* d_ws, size_t ws_size,
                              hipStream_t stream) {
    const float* values = (const float*)d_in[0];
    // d_in[1] = queries: only its length matters (Lq == L)
    const unsigned char* mask = (const unsigned char*)d_in[2];
    const float* Win  = (const float*)d_in[3];
    const float* Wout = (const float*)d_in[4];
    float* out = (float*)d_out;

    const int M = BATCH * SEQL;   // 8192
    const int N = EMB;            // 1024
    const int K = EMB;            // 1024

    u16* VG    = (u16*)d_ws;                              // 8*1032*1024 (16.9 MB)
    u16* Attb  = VG + (size_t)BATCH * VROWS * EMB;        // 16 MB
    u16* Winb  = Attb + (size_t)M * EMB;                  // 2 MB
    u16* Woutb = Winb + (size_t)EMB * EMB;                // 2 MB (~37 MB total)

    // 8256 row blocks + 1024 weight-cvt blocks = 9280
    smooth_direct<<<BATCH * VROWS + 1024, 256, 0, stream>>>(
        values, mask, Win, Wout, VG, Winb, Woutb);

    dim3 ggrid((M / BM) * (N / BN));   // 256 WGs
    gemm_nt_pipe<true,  true ><<<ggrid, 512, 0, stream>>>(VG,   Winb,  Attb, M, N, K);
    gemm_nt_pipe<false, false><<<ggrid, 512, 0, stream>>>(Attb, Woutb, out,  M, N, K);
}

// Round 9
// 65.375 us; speedup vs baseline: 11.0186x; 1.1582x over previous
//
#include <hip/hip_runtime.h>
#include <hip/hip_bf16.h>
#include <cstddef>

// B=8, L=1024, E=1024, H=8, d=128
// out = BandedGaussianAttn(values @ Win^T) @ Wout^T
// Identity (R4/R7/R8-proven): equal stds -> smoothing commutes with projection;
// per-head offset = row shift of GEMM1's A operand (BN=128 == one head).
// Pipeline (3 kernels):
//   smooth_direct4: VG[b,r,:] = bf16(sum_j w[j]*values[b,r-4+j,:])
//                   4-row groups/thread, branchless clamped taps (no spill),
//                   fp32 in -> bf16 out, + weight cvt tail blocks
//   GEMM1: Attb = VG(shifted rows) @ Winb^T   bf16->bf16   (R7-proven)
//   GEMM2: out  = Attb @ Woutb^T              bf16->fp32   (R7-proven)

#define BATCH 8
#define SEQL  1024
#define EMB   1024
#define VROWS 1032   // VG row r holds smoothed source row p = r-4

typedef unsigned short u16;
typedef __attribute__((ext_vector_type(8))) short s16x8;
typedef __attribute__((ext_vector_type(4))) float f32x4;
typedef __attribute__((ext_vector_type(8))) unsigned short u16x8;
typedef __attribute__((ext_vector_type(4))) unsigned short u16x4;

#define GLOAD_LDS16(g, l)                                                     \
    __builtin_amdgcn_global_load_lds(                                         \
        (const __attribute__((address_space(1))) void*)(g),                   \
        (__attribute__((address_space(3))) void*)(l), 16, 0, 0)

__device__ __forceinline__ u16 f2bf(float f) {
    unsigned u = __builtin_bit_cast(unsigned, f);
    u += 0x7FFF + ((u >> 16) & 1);
    return (u16)(u >> 16);
}

__constant__ float c_w[13] = {
    6.075882849823286e-09f, 1.4867195147342979e-06f, 1.3383022576488537e-04f,
    4.431848411938008e-03f, 5.399096651318806e-02f,  2.4197072451914337e-01f,
    3.989422804014327e-01f,
    2.4197072451914337e-01f, 5.399096651318806e-02f, 4.431848411938008e-03f,
    1.3383022576488537e-04f, 1.4867195147342979e-06f, 6.075882849823286e-09f
};
__constant__ int c_ofs[8] = { -3, -2, -1, 0, 0, 1, 2, 3 };

// ---------- smooth_direct4: fused 13-tap smoothing, 4 output rows/thread ----------
// blocks [0, 2064): b = blk&7 (batch pinned to one XCD for tap-window L2 reuse),
//   g = blk>>3 -> VG rows 4g..4g+3 (source p = r-4). Thread owns one float4
//   column chunk. 16 input rows read once, scattered into 4 accumulators with
//   compile-time indices; loads clamped + validity folded into a scalar factor
//   (straight-line code: no predication -> no R5-style spill).
// blocks [2064, 3088): fp32->bf16 cvt of Win/Wout.
__global__ __launch_bounds__(256) void smooth_direct4(
    const float* __restrict__ values, const unsigned char* __restrict__ mask,
    const float* __restrict__ wi, const float* __restrict__ wo,
    u16* __restrict__ VG, u16* __restrict__ wib, u16* __restrict__ wob)
{
    const int blk = blockIdx.x;
    const int NS = BATCH * (VROWS / 4);          // 2064
    if (blk < NS) {
        const int b  = blk & 7;
        const int g  = blk >> 3;                 // 0..257
        const int r0 = g * 4;                    // VG rows r0..r0+3
        const int c  = threadIdx.x * 4;
        const float* vb = values + (size_t)b * SEQL * EMB + c;
        const unsigned char* mrow = mask + b * SEQL;

        f32x4 acc[4] = {};
        #pragma unroll
        for (int i = 0; i < 16; ++i) {           // input rows v = r0-10+i
            const int v  = r0 - 10 + i;
            const int vc = v < 0 ? 0 : (v > SEQL - 1 ? SEQL - 1 : v);
            const float f = ((unsigned)v < (unsigned)SEQL && !mrow[vc]) ? 1.f : 0.f;
            const float4 x = *(const float4*)(vb + (size_t)vc * EMB);
            const float x0 = x.x * f, x1 = x.y * f, x2 = x.z * f, x3 = x.w * f;
            #pragma unroll
            for (int k = 0; k < 4; ++k) {
                const int j = i - k;             // compile-time tap index
                if (j < 0 || j > 12) continue;   // resolved at compile time
                const float w = c_w[j];
                acc[k][0] = fmaf(w, x0, acc[k][0]);
                acc[k][1] = fmaf(w, x1, acc[k][1]);
                acc[k][2] = fmaf(w, x2, acc[k][2]);
                acc[k][3] = fmaf(w, x3, acc[k][3]);
            }
        }
        u16* og = VG + (size_t)(b * VROWS + r0) * EMB + c;
        #pragma unroll
        for (int k = 0; k < 4; ++k) {
            u16x4 o;
            o[0] = f2bf(acc[k][0]); o[1] = f2bf(acc[k][1]);
            o[2] = f2bf(acc[k][2]); o[3] = f2bf(acc[k][3]);
            *(u16x4*)(og + (size_t)k * EMB) = o;
        }
    } else {
        const int k = (blk - NS) * 256 + threadIdx.x;   // 0..262143
        const float* src = (k < 131072) ? wi : wo;
        u16* dst = (k < 131072) ? wib : wob;
        const size_t off = (size_t)(k & 131071) * 8;
        const float4 a = *(const float4*)(src + off);
        const float4 b4 = *(const float4*)(src + off + 4);
        u16x8 o;
        o[0] = f2bf(a.x);  o[1] = f2bf(a.y);  o[2] = f2bf(a.z);  o[3] = f2bf(a.w);
        o[4] = f2bf(b4.x); o[5] = f2bf(b4.y); o[6] = f2bf(b4.z); o[7] = f2bf(b4.w);
        *(u16x8*)(dst + off) = o;
    }
}

// ---------- pipelined bf16 MFMA GEMM: C[M,N] = A[M,K]*B[N,K]^T (R7/R8-proven) ----------
// BM=256 BN=128 BK=64, 512 thr / 8 waves (4M x 2N, per-wave 64x64).
// 3-buffer LDS, 2 fine phases per K-tile, vmcnt(6) counted waits,
// T2 XOR-chunk swizzle, T5 setprio, T1 XCD swizzle.
constexpr int BM = 256, BN = 128, BK = 64;
constexpr int A_EL = BM * BK;
constexpr int B_EL = BN * BK;
constexpr int BUF_EL = A_EL + B_EL;      // 48 KB x3 = 144 KB

template <bool OUT_BF16, bool SHIFTED>
__global__ __launch_bounds__(512, 2) void gemm_nt_pipe(
    const u16* __restrict__ A, const u16* __restrict__ B,
    void* __restrict__ Cout, int M, int N, int K)
{
    __shared__ u16 lds[3 * BUF_EL];

    const int tid  = threadIdx.x;
    const int lane = tid & 63;
    const int wave = tid >> 6;

    const int nwg = gridDim.x;
    const int bid = blockIdx.x;
    const int swz = (bid & 7) * (nwg >> 3) + (bid >> 3);
    const int ntn = N >> 7;
    const int row0 = (swz / ntn) * BM;
    const int col0 = (swz % ntn) * BN;

    int arow0;
    if (SHIFTED) {
        const int b  = row0 >> 10;            // BM=256 | 1024: no batch straddle
        const int q0 = row0 & (SEQL - 1);
        arow0 = b * VROWS + q0 + 4 + c_ofs[col0 >> 7];
    } else {
        arow0 = row0;
    }
    const u16* Ab = A + (size_t)arow0 * K;
    const u16* Bb = B + (size_t)col0 * K;

    const int wm = wave >> 1;
    const int wn = wave & 1;
    const int fr = lane & 15;
    const int fg = lane >> 4;

    const int srow   = tid >> 3;
    const int schunk = tid & 7;

    f32x4 acc[4][4] = {};
    s16x8 af[4][2], bf0[2][2], bf1[2][2];

    auto stageA3 = [&](int bsel, int kt) {
        u16* Abuf = lds + bsel * BUF_EL;
        const int k0 = kt << 6;
        #pragma unroll
        for (int c = 0; c < 3; ++c) {
            const int row = c * 64 + srow;
            const int sc  = (schunk ^ (row & 7)) << 3;
            GLOAD_LDS16(Ab + (size_t)row * K + k0 + sc, Abuf + c * 4096 + wave * 512);
        }
    };
    auto stageRest = [&](int bsel, int kt) {
        u16* Abuf = lds + bsel * BUF_EL;
        u16* Bbuf = Abuf + A_EL;
        const int k0 = kt << 6;
        {
            const int row = 192 + srow;
            const int sc  = (schunk ^ (row & 7)) << 3;
            GLOAD_LDS16(Ab + (size_t)row * K + k0 + sc, Abuf + 3 * 4096 + wave * 512);
        }
        #pragma unroll
        for (int c = 0; c < 2; ++c) {
            const int row = c * 64 + srow;
            const int sc  = (schunk ^ (row & 7)) << 3;
            GLOAD_LDS16(Bb + (size_t)row * K + k0 + sc, Bbuf + c * 4096 + wave * 512);
        }
    };

    auto phase0 = [&](int tile, bool doStage) {
        const u16* Abuf = lds + (tile % 3) * BUF_EL;
        const u16* Bbuf = Abuf + A_EL;
        #pragma unroll
        for (int m = 0; m < 4; ++m)
            #pragma unroll
            for (int kk = 0; kk < 2; ++kk) {
                const int row = wm * 64 + m * 16 + fr;
                const int ch  = ((kk << 2) + fg) ^ (row & 7);
                af[m][kk] = *(const s16x8*)(Abuf + row * 64 + ch * 8);
            }
        #pragma unroll
        for (int n = 0; n < 2; ++n)
            #pragma unroll
            for (int kk = 0; kk < 2; ++kk) {
                const int row = wn * 64 + n * 16 + fr;
                const int ch  = ((kk << 2) + fg) ^ (row & 7);
                bf0[n][kk] = *(const s16x8*)(Bbuf + row * 64 + ch * 8);
            }
        if (doStage) stageA3((tile + 2) % 3, tile + 2);
        __builtin_amdgcn_s_barrier();
        asm volatile("s_waitcnt lgkmcnt(0)" ::: "memory");
        __builtin_amdgcn_sched_barrier(0);
        __builtin_amdgcn_s_setprio(1);
        #pragma unroll
        for (int m = 0; m < 4; ++m)
            #pragma unroll
            for (int n = 0; n < 2; ++n)
                #pragma unroll
                for (int kk = 0; kk < 2; ++kk)
                    acc[m][n] = __builtin_amdgcn_mfma_f32_16x16x32_bf16(
                        af[m][kk], bf0[n][kk], acc[m][n], 0, 0, 0);
        __builtin_amdgcn_s_setprio(0);
        __builtin_amdgcn_s_barrier();
    };

    auto phase1 = [&](int tile, int mode /*0: stage+vm6, 1: vm0, 2: none*/) {
        const u16* Abuf = lds + (tile % 3) * BUF_EL;
        const u16* Bbuf = Abuf + A_EL;
        #pragma unroll
        for (int n = 0; n < 2; ++n)
            #pragma unroll
            for (int kk = 0; kk < 2; ++kk) {
                const int row = wn * 64 + (2 + n) * 16 + fr;
                const int ch  = ((kk << 2) + fg) ^ (row & 7);
                bf1[n][kk] = *(const s16x8*)(Bbuf + row * 64 + ch * 8);
            }
        if (mode == 0) {
            stageRest((tile + 2) % 3, tile + 2);
            asm volatile("s_waitcnt vmcnt(6)" ::: "memory");
        } else if (mode == 1) {
            asm volatile("s_waitcnt vmcnt(0)" ::: "memory");
        }
        __builtin_amdgcn_s_barrier();
        asm volatile("s_waitcnt lgkmcnt(0)" ::: "memory");
        __builtin_amdgcn_sched_barrier(0);
        __builtin_amdgcn_s_setprio(1);
        #pragma unroll
        for (int m = 0; m < 4; ++m)
            #pragma unroll
            for (int n = 0; n < 2; ++n)
                #pragma unroll
                for (int kk = 0; kk < 2; ++kk)
                    acc[m][2 + n] = __builtin_amdgcn_mfma_f32_16x16x32_bf16(
                        af[m][kk], bf1[n][kk], acc[m][2 + n], 0, 0, 0);
        __builtin_amdgcn_s_setprio(0);
        __builtin_amdgcn_s_barrier();
    };

    const int NT = K >> 6;

    stageA3(0, 0); stageRest(0, 0);
    stageA3(1, 1); stageRest(1, 1);
    asm volatile("s_waitcnt vmcnt(6)" ::: "memory");
    __builtin_amdgcn_s_barrier();

    for (int t = 0; t < NT - 2; ++t) { phase0(t, true); phase1(t, 0); }
    phase0(NT - 2, false); phase1(NT - 2, 1);
    phase0(NT - 1, false); phase1(NT - 1, 2);

    const int crow0 = row0 + wm * 64 + fg * 4;
    const int ccol0 = col0 + wn * 64 + fr;
    if (OUT_BF16) {
        u16* C = (u16*)Cout;
        #pragma unroll
        for (int m = 0; m < 4; ++m)
            #pragma unroll
            for (int n = 0; n < 4; ++n)
                #pragma unroll
                for (int j = 0; j < 4; ++j)
                    C[(size_t)(crow0 + m * 16 + j) * N + ccol0 + n * 16] =
                        f2bf(acc[m][n][j]);
    } else {
        float* C = (float*)Cout;
        #pragma unroll
        for (int m = 0; m < 4; ++m)
            #pragma unroll
            for (int n = 0; n < 4; ++n)
                #pragma unroll
                for (int j = 0; j < 4; ++j)
                    C[(size_t)(crow0 + m * 16 + j) * N + ccol0 + n * 16] =
                        acc[m][n][j];
    }
}

extern "C" void kernel_launch(void* const* d_in, const int* in_sizes, int n_in,
                              void* d_out, int out_size, void* d_ws, size_t ws_size,
                              hipStream_t stream) {
    const float* values = (const float*)d_in[0];
    // d_in[1] = queries: only its length matters (Lq == L)
    const unsigned char* mask = (const unsigned char*)d_in[2];
    const float* Win  = (const float*)d_in[3];
    const float* Wout = (const float*)d_in[4];
    float* out = (float*)d_out;

    const int M = BATCH * SEQL;   // 8192
    const int N = EMB;            // 1024
    const int K = EMB;            // 1024

    u16* VG    = (u16*)d_ws;                              // 8*1032*1024 (16.9 MB)
    u16* Attb  = VG + (size_t)BATCH * VROWS * EMB;        // 16 MB
    u16* Winb  = Attb + (size_t)M * EMB;                  // 2 MB
    u16* Woutb = Winb + (size_t)EMB * EMB;                // 2 MB (~37 MB total)

    // 2064 smoothing blocks + 1024 weight-cvt blocks
    smooth_direct4<<<BATCH * (VROWS / 4) + 1024, 256, 0, stream>>>(
        values, mask, Win, Wout, VG, Winb, Woutb);

    dim3 ggrid((M / BM) * (N / BN));   // 256 WGs
    gemm_nt_pipe<true,  true ><<<ggrid, 512, 0, stream>>>(VG,   Winb,  Attb, M, N, K);
    gemm_nt_pipe<false, false><<<ggrid, 512, 0, stream>>>(Attb, Woutb, out,  M, N, K);
}

// Round 10
// 62.653 us; speedup vs baseline: 11.4973x; 1.0434x over previous
//
#include <hip/hip_runtime.h>
#include <hip/hip_bf16.h>
#include <cstddef>

// B=8, L=1024, E=1024, H=8, d=128
// out = BandedGaussianAttn(values @ Win^T) @ Wout^T
// Identity (R4..R9-proven): equal stds -> smoothing commutes with projection;
// per-head offset = row shift of GEMM1's A operand (BN=128 == one head).
// Pipeline (3 kernels):
//   smooth_direct8: VG[b,r,:] = bf16(sum_j w[j]*values[b,r-4+j,:]), 9 taps
//                   (RAD=4; dropped mass ~3e-6), 8 rows/thread, branchless
//                   clamped loads (no spill), + weight cvt tail blocks
//   GEMM1: Attb = VG(shifted rows) @ Winb^T   bf16->bf16   (R7-proven)
//   GEMM2: out  = Attb @ Woutb^T              bf16->fp32   (R7-proven)

#define BATCH 8
#define SEQL  1024
#define EMB   1024
#define VROWS 1032   // 129 groups x 8; VG row r holds smoothed source p = r-4

typedef unsigned short u16;
typedef __attribute__((ext_vector_type(8))) short s16x8;
typedef __attribute__((ext_vector_type(4))) float f32x4;
typedef __attribute__((ext_vector_type(8))) unsigned short u16x8;
typedef __attribute__((ext_vector_type(4))) unsigned short u16x4;

#define GLOAD_LDS16(g, l)                                                     \
    __builtin_amdgcn_global_load_lds(                                         \
        (const __attribute__((address_space(1))) void*)(g),                   \
        (__attribute__((address_space(3))) void*)(l), 16, 0, 0)

__device__ __forceinline__ u16 f2bf(float f) {
    unsigned u = __builtin_bit_cast(unsigned, f);
    u += 0x7FFF + ((u >> 16) & 1);
    return (u16)(u >> 16);
}

// 9 taps, j-4..+4 (RAD=4): dropped tail mass ~3e-6 (safe vs 6e-2 threshold)
__constant__ float c_w[9] = {
    1.3383022576488537e-04f, 4.431848411938008e-03f, 5.399096651318806e-02f,
    2.4197072451914337e-01f, 3.989422804014327e-01f, 2.4197072451914337e-01f,
    5.399096651318806e-02f,  4.431848411938008e-03f, 1.3383022576488537e-04f
};
__constant__ int c_ofs[8] = { -3, -2, -1, 0, 0, 1, 2, 3 };

// ---------- smooth_direct8: 9-tap smoothing, 8 output rows/thread ----------
// blocks [0, 1032): b = blk&7 (batch pinned per-XCD), g = blk>>3 ->
//   VG rows 8g..8g+7. Thread owns one float4 column chunk; 16 covering input
//   rows read once (amp 2.0), scattered into 8 accumulators with
//   compile-time indices; clamped loads + validity factors (straight-line).
// blocks [1032, 2056): fp32->bf16 cvt of Win/Wout.
__global__ __launch_bounds__(256) void smooth_direct8(
    const float* __restrict__ values, const unsigned char* __restrict__ mask,
    const float* __restrict__ wi, const float* __restrict__ wo,
    u16* __restrict__ VG, u16* __restrict__ wib, u16* __restrict__ wob)
{
    const int blk = blockIdx.x;
    const int NS = BATCH * (VROWS / 8);          // 1032
    if (blk < NS) {
        const int b  = blk & 7;
        const int g  = blk >> 3;                 // 0..128
        const int r0 = g * 8;                    // VG rows r0..r0+7
        const int c  = threadIdx.x * 4;
        const float* vb = values + (size_t)b * SEQL * EMB + c;
        const unsigned char* mrow = mask + b * SEQL;

        f32x4 acc[8] = {};
        #pragma unroll
        for (int i = 0; i < 16; ++i) {           // input rows v = r0-8+i
            const int v  = r0 - 8 + i;
            const int vc = v < 0 ? 0 : (v > SEQL - 1 ? SEQL - 1 : v);
            const float f = ((unsigned)v < (unsigned)SEQL && !mrow[vc]) ? 1.f : 0.f;
            const float4 x = *(const float4*)(vb + (size_t)vc * EMB);
            const float x0 = x.x * f, x1 = x.y * f, x2 = x.z * f, x3 = x.w * f;
            #pragma unroll
            for (int k = 0; k < 8; ++k) {
                const int j = i - k;             // compile-time tap index
                if (j < 0 || j > 8) continue;    // resolved at compile time
                const float w = c_w[j];
                acc[k][0] = fmaf(w, x0, acc[k][0]);
                acc[k][1] = fmaf(w, x1, acc[k][1]);
                acc[k][2] = fmaf(w, x2, acc[k][2]);
                acc[k][3] = fmaf(w, x3, acc[k][3]);
            }
        }
        u16* og = VG + (size_t)(b * VROWS + r0) * EMB + c;
        #pragma unroll
        for (int k = 0; k < 8; ++k) {
            u16x4 o;
            o[0] = f2bf(acc[k][0]); o[1] = f2bf(acc[k][1]);
            o[2] = f2bf(acc[k][2]); o[3] = f2bf(acc[k][3]);
            *(u16x4*)(og + (size_t)k * EMB) = o;
        }
    } else {
        const int k = (blk - NS) * 256 + threadIdx.x;   // 0..262143
        const float* src = (k < 131072) ? wi : wo;
        u16* dst = (k < 131072) ? wib : wob;
        const size_t off = (size_t)(k & 131071) * 8;
        const float4 a = *(const float4*)(src + off);
        const float4 b4 = *(const float4*)(src + off + 4);
        u16x8 o;
        o[0] = f2bf(a.x);  o[1] = f2bf(a.y);  o[2] = f2bf(a.z);  o[3] = f2bf(a.w);
        o[4] = f2bf(b4.x); o[5] = f2bf(b4.y); o[6] = f2bf(b4.z); o[7] = f2bf(b4.w);
        *(u16x8*)(dst + off) = o;
    }
}

// ---------- pipelined bf16 MFMA GEMM: C[M,N] = A[M,K]*B[N,K]^T (R7/R8/R9-proven) ----------
// BM=256 BN=128 BK=64, 512 thr / 8 waves (4M x 2N, per-wave 64x64).
// 3-buffer LDS, 2 fine phases per K-tile, vmcnt(6) counted waits,
// T2 XOR-chunk swizzle, T5 setprio, T1 XCD swizzle.
constexpr int BM = 256, BN = 128, BK = 64;
constexpr int A_EL = BM * BK;
constexpr int B_EL = BN * BK;
constexpr int BUF_EL = A_EL + B_EL;      // 48 KB x3 = 144 KB

template <bool OUT_BF16, bool SHIFTED>
__global__ __launch_bounds__(512, 2) void gemm_nt_pipe(
    const u16* __restrict__ A, const u16* __restrict__ B,
    void* __restrict__ Cout, int M, int N, int K)
{
    __shared__ u16 lds[3 * BUF_EL];

    const int tid  = threadIdx.x;
    const int lane = tid & 63;
    const int wave = tid >> 6;

    const int nwg = gridDim.x;
    const int bid = blockIdx.x;
    const int swz = (bid & 7) * (nwg >> 3) + (bid >> 3);
    const int ntn = N >> 7;
    const int row0 = (swz / ntn) * BM;
    const int col0 = (swz % ntn) * BN;

    int arow0;
    if (SHIFTED) {
        const int b  = row0 >> 10;            // BM=256 | 1024: no batch straddle
        const int q0 = row0 & (SEQL - 1);
        arow0 = b * VROWS + q0 + 4 + c_ofs[col0 >> 7];
    } else {
        arow0 = row0;
    }
    const u16* Ab = A + (size_t)arow0 * K;
    const u16* Bb = B + (size_t)col0 * K;

    const int wm = wave >> 1;
    const int wn = wave & 1;
    const int fr = lane & 15;
    const int fg = lane >> 4;

    const int srow   = tid >> 3;
    const int schunk = tid & 7;

    f32x4 acc[4][4] = {};
    s16x8 af[4][2], bf0[2][2], bf1[2][2];

    auto stageA3 = [&](int bsel, int kt) {
        u16* Abuf = lds + bsel * BUF_EL;
        const int k0 = kt << 6;
        #pragma unroll
        for (int c = 0; c < 3; ++c) {
            const int row = c * 64 + srow;
            const int sc  = (schunk ^ (row & 7)) << 3;
            GLOAD_LDS16(Ab + (size_t)row * K + k0 + sc, Abuf + c * 4096 + wave * 512);
        }
    };
    auto stageRest = [&](int bsel, int kt) {
        u16* Abuf = lds + bsel * BUF_EL;
        u16* Bbuf = Abuf + A_EL;
        const int k0 = kt << 6;
        {
            const int row = 192 + srow;
            const int sc  = (schunk ^ (row & 7)) << 3;
            GLOAD_LDS16(Ab + (size_t)row * K + k0 + sc, Abuf + 3 * 4096 + wave * 512);
        }
        #pragma unroll
        for (int c = 0; c < 2; ++c) {
            const int row = c * 64 + srow;
            const int sc  = (schunk ^ (row & 7)) << 3;
            GLOAD_LDS16(Bb + (size_t)row * K + k0 + sc, Bbuf + c * 4096 + wave * 512);
        }
    };

    auto phase0 = [&](int tile, bool doStage) {
        const u16* Abuf = lds + (tile % 3) * BUF_EL;
        const u16* Bbuf = Abuf + A_EL;
        #pragma unroll
        for (int m = 0; m < 4; ++m)
            #pragma unroll
            for (int kk = 0; kk < 2; ++kk) {
                const int row = wm * 64 + m * 16 + fr;
                const int ch  = ((kk << 2) + fg) ^ (row & 7);
                af[m][kk] = *(const s16x8*)(Abuf + row * 64 + ch * 8);
            }
        #pragma unroll
        for (int n = 0; n < 2; ++n)
            #pragma unroll
            for (int kk = 0; kk < 2; ++kk) {
                const int row = wn * 64 + n * 16 + fr;
                const int ch  = ((kk << 2) + fg) ^ (row & 7);
                bf0[n][kk] = *(const s16x8*)(Bbuf + row * 64 + ch * 8);
            }
        if (doStage) stageA3((tile + 2) % 3, tile + 2);
        __builtin_amdgcn_s_barrier();
        asm volatile("s_waitcnt lgkmcnt(0)" ::: "memory");
        __builtin_amdgcn_sched_barrier(0);
        __builtin_amdgcn_s_setprio(1);
        #pragma unroll
        for (int m = 0; m < 4; ++m)
            #pragma unroll
            for (int n = 0; n < 2; ++n)
                #pragma unroll
                for (int kk = 0; kk < 2; ++kk)
                    acc[m][n] = __builtin_amdgcn_mfma_f32_16x16x32_bf16(
                        af[m][kk], bf0[n][kk], acc[m][n], 0, 0, 0);
        __builtin_amdgcn_s_setprio(0);
        __builtin_amdgcn_s_barrier();
    };

    auto phase1 = [&](int tile, int mode /*0: stage+vm6, 1: vm0, 2: none*/) {
        const u16* Abuf = lds + (tile % 3) * BUF_EL;
        const u16* Bbuf = Abuf + A_EL;
        #pragma unroll
        for (int n = 0; n < 2; ++n)
            #pragma unroll
            for (int kk = 0; kk < 2; ++kk) {
                const int row = wn * 64 + (2 + n) * 16 + fr;
                const int ch  = ((kk << 2) + fg) ^ (row & 7);
                bf1[n][kk] = *(const s16x8*)(Bbuf + row * 64 + ch * 8);
            }
        if (mode == 0) {
            stageRest((tile + 2) % 3, tile + 2);
            asm volatile("s_waitcnt vmcnt(6)" ::: "memory");
        } else if (mode == 1) {
            asm volatile("s_waitcnt vmcnt(0)" ::: "memory");
        }
        __builtin_amdgcn_s_barrier();
        asm volatile("s_waitcnt lgkmcnt(0)" ::: "memory");
        __builtin_amdgcn_sched_barrier(0);
        __builtin_amdgcn_s_setprio(1);
        #pragma unroll
        for (int m = 0; m < 4; ++m)
            #pragma unroll
            for (int n = 0; n < 2; ++n)
                #pragma unroll
                for (int kk = 0; kk < 2; ++kk)
                    acc[m][2 + n] = __builtin_amdgcn_mfma_f32_16x16x32_bf16(
                        af[m][kk], bf1[n][kk], acc[m][2 + n], 0, 0, 0);
        __builtin_amdgcn_s_setprio(0);
        __builtin_amdgcn_s_barrier();
    };

    const int NT = K >> 6;

    stageA3(0, 0); stageRest(0, 0);
    stageA3(1, 1); stageRest(1, 1);
    asm volatile("s_waitcnt vmcnt(6)" ::: "memory");
    __builtin_amdgcn_s_barrier();

    for (int t = 0; t < NT - 2; ++t) { phase0(t, true); phase1(t, 0); }
    phase0(NT - 2, false); phase1(NT - 2, 1);
    phase0(NT - 1, false); phase1(NT - 1, 2);

    const int crow0 = row0 + wm * 64 + fg * 4;
    const int ccol0 = col0 + wn * 64 + fr;
    if (OUT_BF16) {
        u16* C = (u16*)Cout;
        #pragma unroll
        for (int m = 0; m < 4; ++m)
            #pragma unroll
            for (int n = 0; n < 4; ++n)
                #pragma unroll
                for (int j = 0; j < 4; ++j)
                    C[(size_t)(crow0 + m * 16 + j) * N + ccol0 + n * 16] =
                        f2bf(acc[m][n][j]);
    } else {
        float* C = (float*)Cout;
        #pragma unroll
        for (int m = 0; m < 4; ++m)
            #pragma unroll
            for (int n = 0; n < 4; ++n)
                #pragma unroll
                for (int j = 0; j < 4; ++j)
                    C[(size_t)(crow0 + m * 16 + j) * N + ccol0 + n * 16] =
                        acc[m][n][j];
    }
}

extern "C" void kernel_launch(void* const* d_in, const int* in_sizes, int n_in,
                              void* d_out, int out_size, void* d_ws, size_t ws_size,
                              hipStream_t stream) {
    const float* values = (const float*)d_in[0];
    // d_in[1] = queries: only its length matters (Lq == L)
    const unsigned char* mask = (const unsigned char*)d_in[2];
    const float* Win  = (const float*)d_in[3];
    const float* Wout = (const float*)d_in[4];
    float* out = (float*)d_out;

    const int M = BATCH * SEQL;   // 8192
    const int N = EMB;            // 1024
    const int K = EMB;            // 1024

    u16* VG    = (u16*)d_ws;                              // 8*1032*1024 (16.9 MB)
    u16* Attb  = VG + (size_t)BATCH * VROWS * EMB;        // 16 MB
    u16* Winb  = Attb + (size_t)M * EMB;                  // 2 MB
    u16* Woutb = Winb + (size_t)EMB * EMB;                // 2 MB (~37 MB total)

    // 1032 smoothing blocks + 1024 weight-cvt blocks
    smooth_direct8<<<BATCH * (VROWS / 8) + 1024, 256, 0, stream>>>(
        values, mask, Win, Wout, VG, Winb, Woutb);

    dim3 ggrid((M / BM) * (N / BN));   // 256 WGs
    gemm_nt_pipe<true,  true ><<<ggrid, 512, 0, stream>>>(VG,   Winb,  Attb, M, N, K);
    gemm_nt_pipe<false, false><<<ggrid, 512, 0, stream>>>(Attb, Woutb, out,  M, N, K);
}